// Round 12
// baseline (137.132 us; speedup 1.0000x reference)
//
#include <hip/hip_runtime.h>

typedef unsigned short u16;
typedef __attribute__((ext_vector_type(8))) short bf16x8;   // 8 bf16 in 4 VGPRs (guide §3)
typedef __attribute__((ext_vector_type(4))) float f32x4;
typedef __attribute__((ext_vector_type(16))) float f32x16;

#define S_LEN 2048
#define BATCH 2
#define HID 1024
#define NH 16
#define HD 64
#define MROWS 4096            // S*B
#define QKV_N 3072
// 0.125 * log2(e): fold head-dim scale + exp->exp2 conversion into Q
#define QSCALE 0.18033688011112042f

__device__ __forceinline__ u16 f2bf(float f) {
  unsigned u = __float_as_uint(f);
  u += 0x7fffu + ((u >> 16) & 1u);           // round-to-nearest-even
  return (u16)(u >> 16);
}

__device__ __forceinline__ float bf2f(u16 u) {
  return __uint_as_float((unsigned)u << 16);
}

__device__ __forceinline__ float fexp2(float x) {
  float r; asm("v_exp_f32 %0, %1" : "=v"(r) : "v"(x)); return r;
}

__device__ __forceinline__ unsigned cvtpk(float lo, float hi) {
  unsigned r; asm("v_cvt_pk_bf16_f32 %0, %1, %2" : "=v"(r) : "v"(lo), "v"(hi)); return r;
}

__device__ __forceinline__ void gl2lds16(const u16* src, u16* lds) {
  __builtin_amdgcn_global_load_lds((__attribute__((address_space(1))) void*)(void*)src,
                                   (__attribute__((address_space(3))) void*)(void*)lds,
                                   16, 0, 0);
}

// ---------------- fused prep: cast x, transpose-cast W_qkv/W_out, rope table ----------------
__device__ __forceinline__ void castT_body(const float* __restrict__ W, u16* __restrict__ Wt,
                                           int Ncols, int Krows, int bx, int by,
                                           float (*tile)[33]) {
  int c0 = bx * 32, r0 = by * 32;
  int tx = threadIdx.x & 31, ty = threadIdx.x >> 5;   // ty in 0..7
  #pragma unroll
  for (int i = 0; i < 4; ++i)
    tile[ty + i * 8][tx] = W[(size_t)(r0 + ty + i * 8) * Ncols + c0 + tx];
  __syncthreads();
  #pragma unroll
  for (int i = 0; i < 4; ++i) {
    int a = ty + i * 8;
    Wt[(size_t)(c0 + a) * Krows + r0 + tx] = f2bf(tile[tx][a]);
  }
}

__global__ __launch_bounds__(256) void prep(
    const float* __restrict__ x, const float* __restrict__ W_qkv,
    const float* __restrict__ W_out, u16* __restrict__ xb,
    u16* __restrict__ Wqt, u16* __restrict__ Wot, float2* __restrict__ rope) {
  __shared__ float tile[32][33];
  const int bid = blockIdx.x;
  if (bid < 2048) {                       // cast x -> bf16, 8 elems/thread
    int i = bid * 256 + threadIdx.x;
    const float4* p = (const float4*)x;
    float4 a = p[2 * i], b = p[2 * i + 1];
    union { u16 us[8]; uint4 v; } o;
    o.us[0] = f2bf(a.x); o.us[1] = f2bf(a.y); o.us[2] = f2bf(a.z); o.us[3] = f2bf(a.w);
    o.us[4] = f2bf(b.x); o.us[5] = f2bf(b.y); o.us[6] = f2bf(b.z); o.us[7] = f2bf(b.w);
    *(uint4*)&xb[8 * i] = o.v;
  } else if (bid < 2048 + 3072) {         // W_qkv [1024][3072] -> Wqt [3072][1024]
    int r = bid - 2048;
    castT_body(W_qkv, Wqt, QKV_N, HID, r % 96, r / 96, tile);
  } else if (bid < 2048 + 3072 + 1024) {  // W_out [1024][1024] -> Wot [1024][1024]^T
    int r = bid - (2048 + 3072);
    castT_body(W_out, Wot, HID, HID, r % 32, r / 32, tile);
  } else {                                // rope table [2048][32] of (cos, sin)
    int i = (bid - 6144) * 256 + threadIdx.x;   // 65536
    int s = i >> 5, j = i & 31;
    float invf = fexp2(-(float)(2 * j) * (13.287712379549449f / 64.0f));  // 10000^(-2j/64)
    float ang = (float)s * invf;
    rope[i] = make_float2(cosf(ang), sinf(ang));
  }
}

// ---------------- GEMM1: qkv = xb @ Wqt^T, fused bias+rotary epilogue ----------------
// V columns are written DIRECTLY transposed to Vt [bh][d][s] via an in-LDS
// 2x[64][64] transpose (XOR-swizzled columns; coalesced uint4 stores).
__global__ __launch_bounds__(256, 2) void gemm_qkv(
    const u16* __restrict__ A, const u16* __restrict__ Bt,
    const float* __restrict__ bias, const float2* __restrict__ rope,
    u16* __restrict__ Qb, u16* __restrict__ Kb, u16* __restrict__ VtOut) {
  __shared__ u16 As[128 * 32];
  __shared__ u16 Bs[128 * 32];
  __shared__ u16 vt[2][64][64];     // V transpose staging (b = batch parity)
  const int tid = threadIdx.x;
  const int lane = tid & 63, wid = tid >> 6;
  const int g = lane >> 4, l15 = lane & 15;
  const int bm0 = blockIdx.x * 128, bn0 = blockIdx.y * 128;
  const int wm = wid >> 1, wn = wid & 1;

  f32x4 acc[4][4] = {};
  for (int kt = 0; kt < 32; ++kt) {
    const int k0 = kt * 32;
    __syncthreads();
    #pragma unroll
    for (int it = 0; it < 2; ++it) {
      int s = it * 256 + tid;
      gl2lds16(A  + (size_t)(bm0 + (s >> 2)) * 1024 + k0 + (s & 3) * 8, &As[s * 8]);
      gl2lds16(Bt + (size_t)(bn0 + (s >> 2)) * 1024 + k0 + (s & 3) * 8, &Bs[s * 8]);
    }
    __syncthreads();
    bf16x8 af[4], bfr[4];
    #pragma unroll
    for (int m = 0; m < 4; ++m) af[m]  = *(const bf16x8*)&As[(wm * 64 + m * 16 + l15) * 32 + g * 8];
    #pragma unroll
    for (int n = 0; n < 4; ++n) bfr[n] = *(const bf16x8*)&Bs[(wn * 64 + n * 16 + l15) * 32 + g * 8];
    #pragma unroll
    for (int m = 0; m < 4; ++m)
      #pragma unroll
      for (int n = 0; n < 4; ++n)
        acc[m][n] = __builtin_amdgcn_mfma_f32_16x16x32_bf16(af[m], bfr[n], acc[m][n], 0, 0, 0);
  }

  const int cw0 = bn0 + wn * 64;
  const int gi = cw0 >> 6;                 // 64-col group id; c = h*192 + t*64 + d
  const int h = gi / 3, tt = gi % 3;       // tt: 0=q 1=k 2=v
  float bs[4];
  #pragma unroll
  for (int n = 0; n < 4; ++n) bs[n] = bias[cw0 + n * 16 + l15];
  const size_t hb = (size_t)h * (S_LEN * HD);

  if (tt == 2) {
    // phase 1: write V quadrant into vt transposed: vt[b][d][srow_local ^ swz]
    #pragma unroll
    for (int m = 0; m < 4; ++m)
      #pragma unroll
      for (int reg = 0; reg < 4; ++reg) {
        int rl = wm * 64 + m * 16 + g * 4 + reg;   // local row (bm0 even)
        int srow = rl >> 1, b = reg & 1;
        #pragma unroll
        for (int n = 0; n < 4; ++n) {
          int d = n * 16 + l15;
          vt[b][d][srow ^ ((d & 7) << 3)] = f2bf(acc[m][n][reg] + bs[n]);
        }
      }
  } else {
    u16* dst = (tt == 0) ? Qb : Kb;
    const float scl = (tt == 0) ? QSCALE : 1.0f;
    #pragma unroll
    for (int m = 0; m < 4; ++m)
      #pragma unroll
      for (int reg = 0; reg < 4; ++reg) {
        int r = bm0 + wm * 64 + m * 16 + g * 4 + reg;
        int srow = r >> 1, b = r & 1;
        size_t o = (size_t)(b * NH) * (S_LEN * HD) + hb + (size_t)srow * HD;
        #pragma unroll
        for (int n = 0; n < 2; ++n) {          // pair (d, d+32) = frags (n, n+2)
          int dlo = n * 16 + l15;              // < 32
          float2 cs = rope[srow * 32 + dlo];
          float v1 = acc[m][n][reg] + bs[n];
          float v2 = acc[m][n + 2][reg] + bs[n + 2];
          dst[o + dlo]      = f2bf((v1 * cs.x - v2 * cs.y) * scl);
          dst[o + dlo + 32] = f2bf((v2 * cs.x + v1 * cs.y) * scl);
        }
      }
  }
  __syncthreads();
  if (tt == 2) {
    // phase 2: coalesced transposed store Vt[(b*NH+h)][d][s0g + srow]
    const int vtid = wm * 64 + lane;        // 0..127 across the two V waves
    const int s0g = bm0 >> 1;
    #pragma unroll
    for (int it = 0; it < 8; ++it) {
      int task = vtid + it * 128;           // 1024 = 2b x 64d x 8 chunks
      int b = task >> 9, d = (task >> 3) & 63, ch = task & 7;
      uint4 v = *(const uint4*)&vt[b][d][(ch ^ (d & 7)) * 8];
      *(uint4*)&VtOut[((size_t)(b * NH + h) * HD + d) * S_LEN + s0g + ch * 8] = v;
    }
  }
}

// ---------------- flash attention v8 (proven 57.4us): 4-wave, 32x32x16, sigma-K, defer-max ----------------
__global__ __launch_bounds__(256, 4) void attn_fwd(
    const u16* __restrict__ Qb, const u16* __restrict__ Kb,
    const u16* __restrict__ Vt, u16* __restrict__ part0,
    u16* __restrict__ part1, float2* __restrict__ stats) {
  __shared__ u16 Ks[2][64 * 64];     // [k-row permuted][d], swizzled chunks
  __shared__ u16 Vs[2][64 * 64];     // [d][k], swizzled chunks
  const int tid = threadIdx.x;
  const int lane = tid & 63, wid = tid >> 6;
  const int l31 = lane & 31, h = lane >> 5;
  const int pp = blockIdx.x & 63;
  const int bh = pp >> 1, split = pp & 1;
  const int kt0 = split * 16;        // 16 k-tiles of 64 per split
  const int qw0 = (blockIdx.x >> 6) * 128 + wid * 32;
  const u16* Qp = Qb + ((size_t)bh * S_LEN + qw0) * HD;
  const u16* Kp = Kb + (size_t)bh * S_LEN * HD;
  const u16* Vp = Vt + (size_t)bh * HD * S_LEN;

  // staging: 512 slots of 16B per buffer, 2 slots/thread (tid, tid+256)
  const int sA = tid, sB = tid + 256;
  const int srA = sA >> 3, srB = sB >> 3;
  const int sswA = (sA & 7) ^ (srA & 7), sswB = (sB & 7) ^ (srB & 7);
  // sigma: actual K row placed at lds row sr (derived from MFMA C/D row mapping)
  #define SIGMA(sr) (((sr >> 4) & 1) * 16 + ((sr >> 2) & 1) * 8 \
                   + (((sr) & 3) | (((sr >> 3) & 1) << 2)) + ((sr) >> 5) * 32)
  const u16* kgA = Kp + (size_t)SIGMA(srA) * HD + sswA * 8;
  const u16* kgB = Kp + (size_t)SIGMA(srB) * HD + sswB * 8;
  const u16* vgA = Vp + (size_t)srA * S_LEN + sswA * 8;
  const u16* vgB = Vp + (size_t)srB * S_LEN + sswB * 8;
  #undef SIGMA

  // Q B-fragments: col=q=l31, d = 16*s + 8*h + j
  bf16x8 qf0 = *(const bf16x8*)&Qp[(size_t)l31 * HD +  0 + h * 8];
  bf16x8 qf1 = *(const bf16x8*)&Qp[(size_t)l31 * HD + 16 + h * 8];
  bf16x8 qf2 = *(const bf16x8*)&Qp[(size_t)l31 * HD + 32 + h * 8];
  bf16x8 qf3 = *(const bf16x8*)&Qp[(size_t)l31 * HD + 48 + h * 8];

  f32x16 po0 = {}, po1 = {};           // C: col=d=l31(+32*dblk), row=q-local
  float mrun = -INFINITY, lrun = 0.f;  // per-lane, q = qw0 + l31

  gl2lds16(kgA + (size_t)kt0 * 64 * HD, &Ks[0][sA * 8]);
  gl2lds16(kgB + (size_t)kt0 * 64 * HD, &Ks[0][sB * 8]);
  gl2lds16(vgA + kt0 * 64, &Vs[0][sA * 8]);
  gl2lds16(vgB + kt0 * 64, &Vs[0][sB * 8]);
  __syncthreads();

  for (int i = 0; i < 16; ++i) {
    const int bb = i & 1;
    if (i + 1 < 16) {            // prefetch next tile into other buffer
      const size_t ko = (size_t)(kt0 + i + 1) * 64 * HD;
      const int vo = (kt0 + i + 1) * 64;
      gl2lds16(kgA + ko, &Ks[bb ^ 1][sA * 8]);
      gl2lds16(kgB + ko, &Ks[bb ^ 1][sB * 8]);
      gl2lds16(vgA + vo, &Vs[bb ^ 1][sA * 8]);
      gl2lds16(vgB + vo, &Vs[bb ^ 1][sB * 8]);
    }
    const u16* KsB = Ks[bb];
    const u16* VsB = Vs[bb];

    // QK^T: A=K (row=k, permuted via sigma), B=Q (col=q)
    f32x16 s0 = {}, s1 = {};
    __builtin_amdgcn_s_setprio(1);
    #pragma unroll
    for (int s = 0; s < 4; ++s) {
      const bf16x8 qf = (s == 0) ? qf0 : (s == 1) ? qf1 : (s == 2) ? qf2 : qf3;
      const int csw = ((2 * s + h) ^ (l31 & 7)) * 8;
      bf16x8 kf0 = *(const bf16x8*)&KsB[l31 * 64 + csw];
      s0 = __builtin_amdgcn_mfma_f32_32x32x16_bf16(kf0, qf, s0, 0, 0, 0);
      bf16x8 kf1 = *(const bf16x8*)&KsB[(32 + l31) * 64 + csw];
      s1 = __builtin_amdgcn_mfma_f32_32x32x16_bf16(kf1, qf, s1, 0, 0, 0);
    }
    __builtin_amdgcn_s_setprio(0);

    // tile max: 32 in-register + 1 cross-half exchange
    float tm = -INFINITY;
    #pragma unroll
    for (int r = 0; r < 16; ++r) tm = fmaxf(tm, fmaxf(s0[r], s1[r]));
    tm = fmaxf(tm, __shfl_xor(tm, 32));

    // T13 defer-max: rescale only if max grew by > 8 (log2 units)
    if (!__all(tm <= mrun + 8.f)) {
      float mnew = fmaxf(mrun, tm);
      float alpha = fexp2(mrun - mnew);
      mrun = mnew;
      lrun *= alpha;
      #pragma unroll
      for (int r = 0; r < 16; ++r) {
        float ar = __shfl(alpha, (r & 3) + 8 * (r >> 2) + 4 * h);
        po0[r] *= ar;
        po1[r] *= ar;
      }
    }

    // exp2 + pack; pw words are already PV A-frag words (sigma)
    float rs = 0.f;
    unsigned pwa[8], pwb[8];
    #pragma unroll
    for (int w = 0; w < 8; ++w) {
      float a = fexp2(s0[2 * w] - mrun), bq = fexp2(s0[2 * w + 1] - mrun);
      rs += a + bq;
      pwa[w] = cvtpk(a, bq);
    }
    #pragma unroll
    for (int w = 0; w < 8; ++w) {
      float a = fexp2(s1[2 * w] - mrun), bq = fexp2(s1[2 * w + 1] - mrun);
      rs += a + bq;
      pwb[w] = cvtpk(a, bq);
    }
    rs += __shfl_xor(rs, 32);
    lrun += rs;

    // PV: A=P (row=q, k=16s+8h+j), B=V (col=d, same k)
    __builtin_amdgcn_s_setprio(1);
    #pragma unroll
    for (int s = 0; s < 4; ++s) {
      union { unsigned w[4]; bf16x8 v; } pf;
      if (s == 0)      { pf.w[0] = pwa[0]; pf.w[1] = pwa[1]; pf.w[2] = pwa[2]; pf.w[3] = pwa[3]; }
      else if (s == 1) { pf.w[0] = pwa[4]; pf.w[1] = pwa[5]; pf.w[2] = pwa[6]; pf.w[3] = pwa[7]; }
      else if (s == 2) { pf.w[0] = pwb[0]; pf.w[1] = pwb[1]; pf.w[2] = pwb[2]; pf.w[3] = pwb[3]; }
      else             { pf.w[0] = pwb[4]; pf.w[1] = pwb[5]; pf.w[2] = pwb[6]; pf.w[3] = pwb[7]; }
      const int csw = ((2 * s + h) ^ (l31 & 7)) * 8;
      bf16x8 vf0 = *(const bf16x8*)&VsB[l31 * 64 + csw];
      po0 = __builtin_amdgcn_mfma_f32_32x32x16_bf16(pf.v, vf0, po0, 0, 0, 0);
      bf16x8 vf1 = *(const bf16x8*)&VsB[(32 + l31) * 64 + csw];
      po1 = __builtin_amdgcn_mfma_f32_32x32x16_bf16(pf.v, vf1, po1, 0, 0, 0);
    }
    __builtin_amdgcn_s_setprio(0);
    __syncthreads();   // drains vmcnt (prefetch landed) + protects buffer swap
  }

  // epilogue: unnormalized partial O (bf16) + stats
  u16* part = split ? part1 : part0;
  if (h == 0)
    stats[(size_t)split * (32 * 2048) + (size_t)bh * 2048 + qw0 + l31] =
        make_float2(mrun, lrun);
  #pragma unroll
  for (int r = 0; r < 16; ++r) {
    int q = qw0 + (r & 3) + 8 * (r >> 2) + 4 * h;
    size_t o = ((size_t)bh * 2048 + q) * 64 + l31;
    part[o]      = f2bf(po0[r]);
    part[o + 32] = f2bf(po1[r]);
  }
}

// ---------------- GEMM2 with FUSED split-combine in the A-staging path ----------------
// out = combine(part0,part1,stats) @ Wot^T + b_out. Each thread's A-row is fixed
// (r = bm0 + tid>>2); per k-iter it loads the two partial 16B chunks + stats
// (L2-hot), combines in registers (identical math to the old attn_combine), and
// ds_write_b128's the A tile. Partial loads issue BEFORE the barrier -> overlap
// with the previous tile's MFMA. BM=64 BN=64, grid 1024, 4 blocks/CU.
__global__ __launch_bounds__(256, 4) void gemm_out(
    const u16* __restrict__ part0, const u16* __restrict__ part1,
    const float2* __restrict__ stats, const u16* __restrict__ Bt,
    const float* __restrict__ bias, float* __restrict__ out) {
  __shared__ u16 As[64 * 32];
  __shared__ u16 Bs[64 * 32];
  const int tid = threadIdx.x;
  const int lane = tid & 63, wid = tid >> 6;   // 4 waves, each 16 rows x 64 cols
  const int g = lane >> 4, l15 = lane & 15;
  const int bm0 = blockIdx.x * 64, bn0 = blockIdx.y * 64;
  const int r = bm0 + (tid >> 2);              // this thread's A row (fixed)
  const int q = r >> 1, bb = r & 1;            // seq pos, batch
  const int ch = (tid & 3) * 8;                // 8-col chunk within 32-col k-slab

  f32x4 acc[4] = {};
  for (int kt = 0; kt < 32; ++kt) {
    const int k0 = kt * 32;
    // ---- fused combine for this thread's A chunk (before barrier: overlaps MFMA) ----
    const int head = kt >> 1;                  // cols k0..k0+32 all in head kt>>1
    const int bh = bb * 16 + head;
    float2 st0 = stats[bh * 2048 + q];
    float2 st1 = stats[32 * 2048 + bh * 2048 + q];
    float M = fmaxf(st0.x, st1.x);
    float w0 = fexp2(st0.x - M), w1 = fexp2(st1.x - M);
    float inv = 1.f / (w0 * st0.y + w1 * st1.y);
    w0 *= inv; w1 *= inv;
    size_t po = ((size_t)bh * 2048 + q) * 64 + (k0 & 32) + ch;
    union { uint4 v; u16 us[8]; } a, c;
    a.v = *(const uint4*)&part0[po];
    c.v = *(const uint4*)&part1[po];
    union { u16 us[8]; uint4 v; } o;
    #pragma unroll
    for (int j = 0; j < 8; ++j)
      o.us[j] = f2bf(w0 * bf2f(a.us[j]) + w1 * bf2f(c.us[j]));
    __syncthreads();                           // previous tile fully consumed
    *(uint4*)&As[tid * 8] = o.v;               // linear ds_write_b128 (2-way = free)
    gl2lds16(Bt + (size_t)(bn0 + (tid >> 2)) * 1024 + k0 + ch, &Bs[tid * 8]);
    __syncthreads();
    bf16x8 af = *(const bf16x8*)&As[(wid * 16 + l15) * 32 + g * 8];
    bf16x8 bfr[4];
    #pragma unroll
    for (int n = 0; n < 4; ++n) bfr[n] = *(const bf16x8*)&Bs[(n * 16 + l15) * 32 + g * 8];
    #pragma unroll
    for (int n = 0; n < 4; ++n)
      acc[n] = __builtin_amdgcn_mfma_f32_16x16x32_bf16(af, bfr[n], acc[n], 0, 0, 0);
  }
  #pragma unroll
  for (int n = 0; n < 4; ++n) {
    int c = bn0 + n * 16 + l15;
    float bv = bias[c];
    #pragma unroll
    for (int reg = 0; reg < 4; ++reg) {
      int rr = bm0 + wid * 16 + g * 4 + reg;
      out[(size_t)rr * HID + c] = acc[n][reg] + bv;
    }
  }
}

extern "C" void kernel_launch(void* const* d_in, const int* in_sizes, int n_in,
                              void* d_out, int out_size, void* d_ws, size_t ws_size,
                              hipStream_t stream) {
  const float* x     = (const float*)d_in[0];
  const float* W_qkv = (const float*)d_in[1];
  const float* b_qkv = (const float*)d_in[2];
  const float* W_out = (const float*)d_in[3];
  const float* b_out = (const float*)d_in[4];
  float* out = (float*)d_out;

  char* ws = (char*)d_ws;
  size_t off = 0;
  auto carve = [&](size_t bytes) { void* p = ws + off; off += (bytes + 255) & ~(size_t)255; return p; };
  u16* xb      = (u16*)carve((size_t)MROWS * HID * 2);       // 8 MB (reused: split-0 partial O)
  u16* Wqt     = (u16*)carve((size_t)QKV_N * HID * 2);       // 6 MB
  u16* Wot     = (u16*)carve((size_t)HID * HID * 2);         // 2 MB
  float2* rope = (float2*)carve((size_t)S_LEN * 32 * 8);     // 512 KB
  u16* Qb      = (u16*)carve((size_t)BATCH * NH * S_LEN * HD * 2);  // 8 MB
  u16* Kb      = (u16*)carve((size_t)BATCH * NH * S_LEN * HD * 2);  // 8 MB
  u16* part1   = (u16*)carve((size_t)BATCH * NH * S_LEN * HD * 2);  // 8 MB (split-1 partial O)
  u16* Vt      = (u16*)carve((size_t)BATCH * NH * S_LEN * HD * 2);  // 8 MB
  float2* stats= (float2*)carve((size_t)2 * 32 * 2048 * 8);  // 1 MB

  prep<<<6400, 256, 0, stream>>>(x, W_qkv, W_out, xb, Wqt, Wot, rope);
  gemm_qkv<<<dim3(MROWS / 128, QKV_N / 128), 256, 0, stream>>>(xb, Wqt, b_qkv, rope, Qb, Kb, Vt);
  // xb (consumed by gemm_qkv) is dead here -> reuse as split-0 partial-O buffer.
  attn_fwd<<<1024, 256, 0, stream>>>(Qb, Kb, Vt, xb, part1, stats);
  gemm_out<<<dim3(MROWS / 64, HID / 64), 256, 0, stream>>>(xb, part1, stats, Wot, b_out, out);
}

// Round 13
// 120.702 us; speedup vs baseline: 1.1361x; 1.1361x over previous
//
#include <hip/hip_runtime.h>

typedef unsigned short u16;
typedef __attribute__((ext_vector_type(8))) short bf16x8;   // 8 bf16 in 4 VGPRs (guide §3)
typedef __attribute__((ext_vector_type(4))) float f32x4;
typedef __attribute__((ext_vector_type(16))) float f32x16;

#define S_LEN 2048
#define BATCH 2
#define HID 1024
#define NH 16
#define HD 64
#define MROWS 4096            // S*B
#define QKV_N 3072
// 0.125 * log2(e): fold head-dim scale + exp->exp2 conversion into Q
#define QSCALE 0.18033688011112042f

__device__ __forceinline__ u16 f2bf(float f) {
  unsigned u = __float_as_uint(f);
  u += 0x7fffu + ((u >> 16) & 1u);           // round-to-nearest-even
  return (u16)(u >> 16);
}

__device__ __forceinline__ float bf2f(u16 u) {
  return __uint_as_float((unsigned)u << 16);
}

__device__ __forceinline__ float fexp2(float x) {
  float r; asm("v_exp_f32 %0, %1" : "=v"(r) : "v"(x)); return r;
}

__device__ __forceinline__ unsigned cvtpk(float lo, float hi) {
  unsigned r; asm("v_cvt_pk_bf16_f32 %0, %1, %2" : "=v"(r) : "v"(lo), "v"(hi)); return r;
}

__device__ __forceinline__ void gl2lds16(const u16* src, u16* lds) {
  __builtin_amdgcn_global_load_lds((__attribute__((address_space(1))) void*)(void*)src,
                                   (__attribute__((address_space(3))) void*)(void*)lds,
                                   16, 0, 0);
}

// ---------------- fused prep: cast x, transpose-cast W_qkv/W_out, rope table ----------------
__device__ __forceinline__ void castT_body(const float* __restrict__ W, u16* __restrict__ Wt,
                                           int Ncols, int Krows, int bx, int by,
                                           float (*tile)[33]) {
  int c0 = bx * 32, r0 = by * 32;
  int tx = threadIdx.x & 31, ty = threadIdx.x >> 5;   // ty in 0..7
  #pragma unroll
  for (int i = 0; i < 4; ++i)
    tile[ty + i * 8][tx] = W[(size_t)(r0 + ty + i * 8) * Ncols + c0 + tx];
  __syncthreads();
  #pragma unroll
  for (int i = 0; i < 4; ++i) {
    int a = ty + i * 8;
    Wt[(size_t)(c0 + a) * Krows + r0 + tx] = f2bf(tile[tx][a]);
  }
}

__global__ __launch_bounds__(256) void prep(
    const float* __restrict__ x, const float* __restrict__ W_qkv,
    const float* __restrict__ W_out, u16* __restrict__ xb,
    u16* __restrict__ Wqt, u16* __restrict__ Wot, float2* __restrict__ rope) {
  __shared__ float tile[32][33];
  const int bid = blockIdx.x;
  if (bid < 2048) {                       // cast x -> bf16, 8 elems/thread
    int i = bid * 256 + threadIdx.x;
    const float4* p = (const float4*)x;
    float4 a = p[2 * i], b = p[2 * i + 1];
    union { u16 us[8]; uint4 v; } o;
    o.us[0] = f2bf(a.x); o.us[1] = f2bf(a.y); o.us[2] = f2bf(a.z); o.us[3] = f2bf(a.w);
    o.us[4] = f2bf(b.x); o.us[5] = f2bf(b.y); o.us[6] = f2bf(b.z); o.us[7] = f2bf(b.w);
    *(uint4*)&xb[8 * i] = o.v;
  } else if (bid < 2048 + 3072) {         // W_qkv [1024][3072] -> Wqt [3072][1024]
    int r = bid - 2048;
    castT_body(W_qkv, Wqt, QKV_N, HID, r % 96, r / 96, tile);
  } else if (bid < 2048 + 3072 + 1024) {  // W_out [1024][1024] -> Wot [1024][1024]^T
    int r = bid - (2048 + 3072);
    castT_body(W_out, Wot, HID, HID, r % 32, r / 32, tile);
  } else {                                // rope table [2048][32] of (cos, sin)
    int i = (bid - 6144) * 256 + threadIdx.x;   // 65536
    int s = i >> 5, j = i & 31;
    float invf = fexp2(-(float)(2 * j) * (13.287712379549449f / 64.0f));  // 10000^(-2j/64)
    float ang = (float)s * invf;
    rope[i] = make_float2(cosf(ang), sinf(ang));
  }
}

// ---------------- GEMM1: qkv = xb @ Wqt^T, fused bias+rotary epilogue ----------------
// V columns are written DIRECTLY transposed to Vt [bh][d][s] via an in-LDS
// 2x[64][64] transpose (XOR-swizzled columns; coalesced uint4 stores).
__global__ __launch_bounds__(256, 2) void gemm_qkv(
    const u16* __restrict__ A, const u16* __restrict__ Bt,
    const float* __restrict__ bias, const float2* __restrict__ rope,
    u16* __restrict__ Qb, u16* __restrict__ Kb, u16* __restrict__ VtOut) {
  __shared__ u16 As[128 * 32];
  __shared__ u16 Bs[128 * 32];
  __shared__ u16 vt[2][64][64];     // V transpose staging (b = batch parity)
  const int tid = threadIdx.x;
  const int lane = tid & 63, wid = tid >> 6;
  const int g = lane >> 4, l15 = lane & 15;
  const int bm0 = blockIdx.x * 128, bn0 = blockIdx.y * 128;
  const int wm = wid >> 1, wn = wid & 1;

  f32x4 acc[4][4] = {};
  for (int kt = 0; kt < 32; ++kt) {
    const int k0 = kt * 32;
    __syncthreads();
    #pragma unroll
    for (int it = 0; it < 2; ++it) {
      int s = it * 256 + tid;
      gl2lds16(A  + (size_t)(bm0 + (s >> 2)) * 1024 + k0 + (s & 3) * 8, &As[s * 8]);
      gl2lds16(Bt + (size_t)(bn0 + (s >> 2)) * 1024 + k0 + (s & 3) * 8, &Bs[s * 8]);
    }
    __syncthreads();
    bf16x8 af[4], bfr[4];
    #pragma unroll
    for (int m = 0; m < 4; ++m) af[m]  = *(const bf16x8*)&As[(wm * 64 + m * 16 + l15) * 32 + g * 8];
    #pragma unroll
    for (int n = 0; n < 4; ++n) bfr[n] = *(const bf16x8*)&Bs[(wn * 64 + n * 16 + l15) * 32 + g * 8];
    #pragma unroll
    for (int m = 0; m < 4; ++m)
      #pragma unroll
      for (int n = 0; n < 4; ++n)
        acc[m][n] = __builtin_amdgcn_mfma_f32_16x16x32_bf16(af[m], bfr[n], acc[m][n], 0, 0, 0);
  }

  const int cw0 = bn0 + wn * 64;
  const int gi = cw0 >> 6;                 // 64-col group id; c = h*192 + t*64 + d
  const int h = gi / 3, tt = gi % 3;       // tt: 0=q 1=k 2=v
  float bs[4];
  #pragma unroll
  for (int n = 0; n < 4; ++n) bs[n] = bias[cw0 + n * 16 + l15];
  const size_t hb = (size_t)h * (S_LEN * HD);

  if (tt == 2) {
    // phase 1: write V quadrant into vt transposed: vt[b][d][srow_local ^ swz]
    #pragma unroll
    for (int m = 0; m < 4; ++m)
      #pragma unroll
      for (int reg = 0; reg < 4; ++reg) {
        int rl = wm * 64 + m * 16 + g * 4 + reg;   // local row (bm0 even)
        int srow = rl >> 1, b = reg & 1;
        #pragma unroll
        for (int n = 0; n < 4; ++n) {
          int d = n * 16 + l15;
          vt[b][d][srow ^ ((d & 7) << 3)] = f2bf(acc[m][n][reg] + bs[n]);
        }
      }
  } else {
    u16* dst = (tt == 0) ? Qb : Kb;
    const float scl = (tt == 0) ? QSCALE : 1.0f;
    #pragma unroll
    for (int m = 0; m < 4; ++m)
      #pragma unroll
      for (int reg = 0; reg < 4; ++reg) {
        int r = bm0 + wm * 64 + m * 16 + g * 4 + reg;
        int srow = r >> 1, b = r & 1;
        size_t o = (size_t)(b * NH) * (S_LEN * HD) + hb + (size_t)srow * HD;
        #pragma unroll
        for (int n = 0; n < 2; ++n) {          // pair (d, d+32) = frags (n, n+2)
          int dlo = n * 16 + l15;              // < 32
          float2 cs = rope[srow * 32 + dlo];
          float v1 = acc[m][n][reg] + bs[n];
          float v2 = acc[m][n + 2][reg] + bs[n + 2];
          dst[o + dlo]      = f2bf((v1 * cs.x - v2 * cs.y) * scl);
          dst[o + dlo + 32] = f2bf((v2 * cs.x + v1 * cs.y) * scl);
        }
      }
  }
  __syncthreads();
  if (tt == 2) {
    // phase 2: coalesced transposed store Vt[(b*NH+h)][d][s0g + srow]
    const int vtid = wm * 64 + lane;        // 0..127 across the two V waves
    const int s0g = bm0 >> 1;
    #pragma unroll
    for (int it = 0; it < 8; ++it) {
      int task = vtid + it * 128;           // 1024 = 2b x 64d x 8 chunks
      int b = task >> 9, d = (task >> 3) & 63, ch = task & 7;
      uint4 v = *(const uint4*)&vt[b][d][(ch ^ (d & 7)) * 8];
      *(uint4*)&VtOut[((size_t)(b * NH + h) * HD + d) * S_LEN + s0g + ch * 8] = v;
    }
  }
}

// ---------------- flash attention v6 (proven 55.7us): 8-wave, 32x32x16, sigma-K, defer-max ----------------
// 512 threads = 8 waves, each wave 32 q-rows (256 q/block); grid 512 (XCD-affine).
// QK^T swapped: C row=k, col=q=lane&31 -> softmax fully lane-local.
// K rows stored PERMUTED in LDS (sigma folded into staging source address) so
// QK's C-row mapping yields P words exactly in PV A-fragment order.
__global__ __launch_bounds__(512, 4) void attn_fwd(
    const u16* __restrict__ Qb, const u16* __restrict__ Kb,
    const u16* __restrict__ Vt, u16* __restrict__ part0,
    u16* __restrict__ part1, float2* __restrict__ stats) {
  __shared__ u16 Ks[2][64 * 64];     // [k-row permuted][d], swizzled chunks
  __shared__ u16 Vs[2][64 * 64];     // [d][k], swizzled chunks
  const int tid = threadIdx.x;
  const int lane = tid & 63, wid = tid >> 6;
  const int l31 = lane & 31, h = lane >> 5;
  const int pp = blockIdx.x & 63;
  const int bh = pp >> 1, split = pp & 1;
  const int kt0 = split * 16;        // 16 k-tiles of 64 per split
  const int qw0 = (blockIdx.x >> 6) * 256 + wid * 32;
  const u16* Qp = Qb + ((size_t)bh * S_LEN + qw0) * HD;
  const u16* Kp = Kb + (size_t)bh * S_LEN * HD;
  const u16* Vp = Vt + (size_t)bh * HD * S_LEN;

  // staging: thread covers lds row sr, 16B chunk tc (bank-swizzled source chunk).
  const int sr = tid >> 3, tc = tid & 7;
  const int ssw = tc ^ (sr & 7);
  // sigma: actual K row placed at lds row sr (derived from MFMA C/D row mapping)
  const int act = ((sr >> 4) & 1) * 16 + ((sr >> 2) & 1) * 8
                + ((sr & 3) | (((sr >> 3) & 1) << 2)) + (sr >> 5) * 32;
  const u16* kg = Kp + (size_t)act * HD + ssw * 8;      // + tile*64*HD per tile
  const u16* vg = Vp + (size_t)sr * S_LEN + ssw * 8;    // + tile*64 per tile

  // Q B-fragments: col=q=l31, d = 16*s + 8*h + j
  bf16x8 qf0 = *(const bf16x8*)&Qp[(size_t)l31 * HD +  0 + h * 8];
  bf16x8 qf1 = *(const bf16x8*)&Qp[(size_t)l31 * HD + 16 + h * 8];
  bf16x8 qf2 = *(const bf16x8*)&Qp[(size_t)l31 * HD + 32 + h * 8];
  bf16x8 qf3 = *(const bf16x8*)&Qp[(size_t)l31 * HD + 48 + h * 8];

  f32x16 po0 = {}, po1 = {};           // C: col=d=l31(+32*dblk), row=q-local
  float mrun = -INFINITY, lrun = 0.f;  // per-lane, q = qw0 + l31

  gl2lds16(kg + (size_t)kt0 * 64 * HD, &Ks[0][tid * 8]);
  gl2lds16(vg + kt0 * 64, &Vs[0][tid * 8]);
  __syncthreads();

  for (int i = 0; i < 16; ++i) {
    const int bb = i & 1;
    if (i + 1 < 16) {            // prefetch next tile into other buffer
      gl2lds16(kg + (size_t)(kt0 + i + 1) * 64 * HD, &Ks[bb ^ 1][tid * 8]);
      gl2lds16(vg + (kt0 + i + 1) * 64, &Vs[bb ^ 1][tid * 8]);
    }
    const u16* KsB = Ks[bb];
    const u16* VsB = Vs[bb];

    // QK^T: A=K (row=k, permuted via sigma), B=Q (col=q)
    f32x16 s0 = {}, s1 = {};
    __builtin_amdgcn_s_setprio(1);
    #pragma unroll
    for (int s = 0; s < 4; ++s) {
      const bf16x8 qf = (s == 0) ? qf0 : (s == 1) ? qf1 : (s == 2) ? qf2 : qf3;
      const int csw = ((2 * s + h) ^ (l31 & 7)) * 8;
      bf16x8 kf0 = *(const bf16x8*)&KsB[l31 * 64 + csw];
      s0 = __builtin_amdgcn_mfma_f32_32x32x16_bf16(kf0, qf, s0, 0, 0, 0);
      bf16x8 kf1 = *(const bf16x8*)&KsB[(32 + l31) * 64 + csw];
      s1 = __builtin_amdgcn_mfma_f32_32x32x16_bf16(kf1, qf, s1, 0, 0, 0);
    }
    __builtin_amdgcn_s_setprio(0);

    // tile max: 32 in-register + 1 cross-half exchange
    float tm = -INFINITY;
    #pragma unroll
    for (int r = 0; r < 16; ++r) tm = fmaxf(tm, fmaxf(s0[r], s1[r]));
    tm = fmaxf(tm, __shfl_xor(tm, 32));

    // T13 defer-max: rescale only if max grew by > 8 (log2 units)
    if (!__all(tm <= mrun + 8.f)) {
      float mnew = fmaxf(mrun, tm);
      float alpha = fexp2(mrun - mnew);
      mrun = mnew;
      lrun *= alpha;
      #pragma unroll
      for (int r = 0; r < 16; ++r) {
        float ar = __shfl(alpha, (r & 3) + 8 * (r >> 2) + 4 * h);
        po0[r] *= ar;
        po1[r] *= ar;
      }
    }

    // exp2 + pack; pw words are already PV A-frag words (sigma)
    float rs = 0.f;
    unsigned pwa[8], pwb[8];
    #pragma unroll
    for (int w = 0; w < 8; ++w) {
      float a = fexp2(s0[2 * w] - mrun), bq = fexp2(s0[2 * w + 1] - mrun);
      rs += a + bq;
      pwa[w] = cvtpk(a, bq);
    }
    #pragma unroll
    for (int w = 0; w < 8; ++w) {
      float a = fexp2(s1[2 * w] - mrun), bq = fexp2(s1[2 * w + 1] - mrun);
      rs += a + bq;
      pwb[w] = cvtpk(a, bq);
    }
    rs += __shfl_xor(rs, 32);
    lrun += rs;

    // PV: A=P (row=q, k=16s+8h+j), B=V (col=d, same k)
    __builtin_amdgcn_s_setprio(1);
    #pragma unroll
    for (int s = 0; s < 4; ++s) {
      union { unsigned w[4]; bf16x8 v; } pf;
      if (s == 0)      { pf.w[0] = pwa[0]; pf.w[1] = pwa[1]; pf.w[2] = pwa[2]; pf.w[3] = pwa[3]; }
      else if (s == 1) { pf.w[0] = pwa[4]; pf.w[1] = pwa[5]; pf.w[2] = pwa[6]; pf.w[3] = pwa[7]; }
      else if (s == 2) { pf.w[0] = pwb[0]; pf.w[1] = pwb[1]; pf.w[2] = pwb[2]; pf.w[3] = pwb[3]; }
      else             { pf.w[0] = pwb[4]; pf.w[1] = pwb[5]; pf.w[2] = pwb[6]; pf.w[3] = pwb[7]; }
      const int csw = ((2 * s + h) ^ (l31 & 7)) * 8;
      bf16x8 vf0 = *(const bf16x8*)&VsB[l31 * 64 + csw];
      po0 = __builtin_amdgcn_mfma_f32_32x32x16_bf16(pf.v, vf0, po0, 0, 0, 0);
      bf16x8 vf1 = *(const bf16x8*)&VsB[(32 + l31) * 64 + csw];
      po1 = __builtin_amdgcn_mfma_f32_32x32x16_bf16(pf.v, vf1, po1, 0, 0, 0);
    }
    __builtin_amdgcn_s_setprio(0);
    __syncthreads();   // drains vmcnt (prefetch landed) + protects buffer swap
  }

  // epilogue: unnormalized partial O (bf16) + stats
  u16* part = split ? part1 : part0;
  if (h == 0)
    stats[(size_t)split * (32 * 2048) + (size_t)bh * 2048 + qw0 + l31] =
        make_float2(mrun, lrun);
  #pragma unroll
  for (int r = 0; r < 16; ++r) {
    int q = qw0 + (r & 3) + 8 * (r >> 2) + 4 * h;
    size_t o = ((size_t)bh * 2048 + q) * 64 + l31;
    part[o]      = f2bf(po0[r]);
    part[o + 32] = f2bf(po1[r]);
  }
}

// ---------------- combine the two k-splits -> attn2d [s*B+b][h*64+d] ----------------
__global__ void attn_combine(const u16* __restrict__ part0, const u16* __restrict__ part1,
                             const float2* __restrict__ stats, u16* __restrict__ attn2d) {
  int t = blockIdx.x * 256 + threadIdx.x;   // 524288 = 32 bh * 2048 q * 8 d-chunks
  int bh = t >> 14, r = t & 16383, q = r >> 3, dc = r & 7;
  int b = bh >> 4, h = bh & 15;
  float2 s0 = stats[bh * 2048 + q];
  float2 s1 = stats[32 * 2048 + bh * 2048 + q];
  float M = fmaxf(s0.x, s1.x);
  float w0 = fexp2(s0.x - M), w1 = fexp2(s1.x - M);
  float inv = 1.f / (w0 * s0.y + w1 * s1.y);
  w0 *= inv; w1 *= inv;
  size_t off = ((size_t)bh * 2048 + q) * 64 + dc * 8;
  union { uint4 v; u16 us[8]; } a, c, o;
  a.v = *(const uint4*)&part0[off];
  c.v = *(const uint4*)&part1[off];
  #pragma unroll
  for (int j = 0; j < 8; ++j)
    o.us[j] = f2bf(w0 * bf2f(a.us[j]) + w1 * bf2f(c.us[j]));
  *(uint4*)&attn2d[((size_t)q * BATCH + b) * HID + h * HD + dc * 8] = o.v;
}

// ---------------- GEMM2: out = attn2d @ Wot^T + b_out (fp32 out), BM=64 BN=64 ----------------
// grid 1024 -> 4 blocks/CU (16 waves) for latency hiding.
__global__ __launch_bounds__(256, 4) void gemm_out(
    const u16* __restrict__ A, const u16* __restrict__ Bt,
    const float* __restrict__ bias, float* __restrict__ out) {
  __shared__ u16 As[64 * 32];
  __shared__ u16 Bs[64 * 32];
  const int tid = threadIdx.x;
  const int lane = tid & 63, wid = tid >> 6;   // 4 waves, each 16 rows x 64 cols
  const int g = lane >> 4, l15 = lane & 15;
  const int bm0 = blockIdx.x * 64, bn0 = blockIdx.y * 64;

  f32x4 acc[4] = {};
  for (int kt = 0; kt < 32; ++kt) {
    const int k0 = kt * 32;
    __syncthreads();
    gl2lds16(A  + (size_t)(bm0 + (tid >> 2)) * 1024 + k0 + (tid & 3) * 8, &As[tid * 8]);
    gl2lds16(Bt + (size_t)(bn0 + (tid >> 2)) * 1024 + k0 + (tid & 3) * 8, &Bs[tid * 8]);
    __syncthreads();
    bf16x8 af = *(const bf16x8*)&As[(wid * 16 + l15) * 32 + g * 8];
    bf16x8 bfr[4];
    #pragma unroll
    for (int n = 0; n < 4; ++n) bfr[n] = *(const bf16x8*)&Bs[(n * 16 + l15) * 32 + g * 8];
    #pragma unroll
    for (int n = 0; n < 4; ++n)
      acc[n] = __builtin_amdgcn_mfma_f32_16x16x32_bf16(af, bfr[n], acc[n], 0, 0, 0);
  }
  #pragma unroll
  for (int n = 0; n < 4; ++n) {
    int c = bn0 + n * 16 + l15;
    float bv = bias[c];
    #pragma unroll
    for (int reg = 0; reg < 4; ++reg) {
      int r = bm0 + wid * 16 + g * 4 + reg;
      out[(size_t)r * HID + c] = acc[n][reg] + bv;
    }
  }
}

extern "C" void kernel_launch(void* const* d_in, const int* in_sizes, int n_in,
                              void* d_out, int out_size, void* d_ws, size_t ws_size,
                              hipStream_t stream) {
  const float* x     = (const float*)d_in[0];
  const float* W_qkv = (const float*)d_in[1];
  const float* b_qkv = (const float*)d_in[2];
  const float* W_out = (const float*)d_in[3];
  const float* b_out = (const float*)d_in[4];
  float* out = (float*)d_out;

  char* ws = (char*)d_ws;
  size_t off = 0;
  auto carve = [&](size_t bytes) { void* p = ws + off; off += (bytes + 255) & ~(size_t)255; return p; };
  u16* xb      = (u16*)carve((size_t)MROWS * HID * 2);       // 8 MB (reused: split-0 partial O)
  u16* Wqt     = (u16*)carve((size_t)QKV_N * HID * 2);       // 6 MB
  u16* Wot     = (u16*)carve((size_t)HID * HID * 2);         // 2 MB
  float2* rope = (float2*)carve((size_t)S_LEN * 32 * 8);     // 512 KB
  u16* Qb      = (u16*)carve((size_t)BATCH * NH * S_LEN * HD * 2);  // 8 MB
  u16* Kb      = (u16*)carve((size_t)BATCH * NH * S_LEN * HD * 2);  // 8 MB
  u16* part1   = (u16*)carve((size_t)BATCH * NH * S_LEN * HD * 2);  // 8 MB (split-1 partial O)
  u16* Vt      = (u16*)carve((size_t)BATCH * NH * S_LEN * HD * 2);  // 8 MB
  u16* attn2d  = (u16*)carve((size_t)MROWS * HID * 2);       // 8 MB
  float2* stats= (float2*)carve((size_t)2 * 32 * 2048 * 8);  // 1 MB

  prep<<<6400, 256, 0, stream>>>(x, W_qkv, W_out, xb, Wqt, Wot, rope);
  gemm_qkv<<<dim3(MROWS / 128, QKV_N / 128), 256, 0, stream>>>(xb, Wqt, b_qkv, rope, Qb, Kb, Vt);
  // xb (consumed by gemm_qkv) is dead here -> reuse as split-0 partial-O buffer.
  attn_fwd<<<512, 512, 0, stream>>>(Qb, Kb, Vt, xb, part1, stats);
  attn_combine<<<2048, 256, 0, stream>>>(xb, part1, stats, attn2d);
  gemm_out<<<dim3(MROWS / 64, HID / 64), 256, 0, stream>>>(attn2d, Wot, b_out, out);
}